// Round 1
// baseline (3831.889 us; speedup 1.0000x reference)
//
#include <hip/hip_runtime.h>

#define H 64
#define NN 100000
#define NE 1000000
#define EPS 1e-6f

// ROUND 7: edge GEMM rewritten lane-per-edge with ZERO LDS.
// Theory: old edge_db was LDS-read-pipe bound (2x ds_read_b128 ~24cy per
// 16 fmac = 32 SIMD-cy; 4 SIMDs share one LDS pipe -> ~3x oversubscribed,
// VALUBusy capped ~25-33%). A-operand has zero cross-lane reuse (each edge
// row feeds exactly one output row), so: each lane owns one edge, acc[64]
// in VGPRs, streams its 3 input rows from global (64B-line chunks,
// prefetched 1 ahead), and reads We rows via wave-uniform addresses ->
// s_load -> SGPR broadcast operand of v_fmac_f32. No LDS, no barriers,
// lane-local LayerNorm. Atomic traffic unchanged vs baseline.

typedef __attribute__((ext_vector_type(4))) float f32v4;

__global__ __launch_bounds__(256, 4) void edge_rowlane(
    const float* __restrict__ nodes, const float* __restrict__ edges,
    const int* __restrict__ senders, const int* __restrict__ receivers,
    const float* __restrict__ We, const float* __restrict__ be,
    const float* __restrict__ ln_s, const float* __restrict__ ln_b,
    float* recv_agg, float* __restrict__ edges_out) {
  const int e = blockIdx.x * 256 + threadIdx.x;
  if (e >= NE) return;  // NE is 64-aligned: exits are whole-wave uniform
  const int s = senders[e];
  const int r = receivers[e];
  const float* pe = edges + (size_t)e * H;
  const float* ps = nodes + (size_t)s * H;
  const float* pr = nodes + (size_t)r * H;

  float acc[H];
#pragma unroll
  for (int c = 0; c < H; ++c) acc[c] = 0.0f;

  // 12 chunks of 16 K-values. Chunk t: region t>>2 (edge/sender/receiver),
  // k-offset (t&3)*16. Each chunk = one 64B line of the source row.
  float4 b0 = *(const float4*)(pe + 0);
  float4 b1 = *(const float4*)(pe + 4);
  float4 b2 = *(const float4*)(pe + 8);
  float4 b3 = *(const float4*)(pe + 12);

#define FMA_ONE(AV, KK)                                                        \
  {                                                                            \
    const float av_ = (AV);                                                    \
    const float* __restrict__ wr_ = wrow + (KK) * H;                           \
    _Pragma("unroll")                                                          \
    for (int c = 0; c < H; ++c) acc[c] = fmaf(wr_[c], av_, acc[c]);            \
  }

#pragma unroll 1  // keep body compact (~1KB FMAs): dynamic t, I$-friendly
  for (int t = 0; t < 12; ++t) {
    float4 n0, n1, n2, n3;
    const int tn = t + 1;
    if (tn < 12) {  // prefetch next chunk; latency hides under 1024 FMAs
      const float* src = (tn < 4) ? pe : ((tn < 8) ? ps : pr);
      src += (tn & 3) * 16;
      n0 = *(const float4*)(src + 0);
      n1 = *(const float4*)(src + 4);
      n2 = *(const float4*)(src + 8);
      n3 = *(const float4*)(src + 12);
    }
    // wrow is wave-uniform (t uniform) -> scalar loads -> SGPR operands
    const float* __restrict__ wrow = We + (size_t)t * (16 * H);
    FMA_ONE(b0.x, 0)  FMA_ONE(b0.y, 1)  FMA_ONE(b0.z, 2)  FMA_ONE(b0.w, 3)
    FMA_ONE(b1.x, 4)  FMA_ONE(b1.y, 5)  FMA_ONE(b1.z, 6)  FMA_ONE(b1.w, 7)
    FMA_ONE(b2.x, 8)  FMA_ONE(b2.y, 9)  FMA_ONE(b2.z, 10) FMA_ONE(b2.w, 11)
    FMA_ONE(b3.x, 12) FMA_ONE(b3.y, 13) FMA_ONE(b3.z, 14) FMA_ONE(b3.w, 15)
    if (tn < 12) { b0 = n0; b1 = n1; b2 = n2; b3 = n3; }
  }
#undef FMA_ONE

  // Epilogue: bias -> scatter-add to recv_agg -> residual -> lane-local LN.
  // Residual loads issued at the top of each group so their vmcnt drains
  // without waiting on the 64 fire-and-forget atomics.
  float* ra = recv_agg + (size_t)r * H;
#pragma unroll
  for (int g = 0; g < 4; ++g) {
    const float* pres = pe + g * 16;
    float4 r0 = *(const float4*)(pres + 0);
    float4 r1 = *(const float4*)(pres + 4);
    float4 r2 = *(const float4*)(pres + 8);
    float4 r3 = *(const float4*)(pres + 12);
    const float res[16] = {r0.x, r0.y, r0.z, r0.w, r1.x, r1.y, r1.z, r1.w,
                           r2.x, r2.y, r2.z, r2.w, r3.x, r3.y, r3.z, r3.w};
#pragma unroll
    for (int j = 0; j < 16; ++j) {
      const int c = g * 16 + j;
      const float n = acc[c] + be[c];
      atomicAdd(ra + c, n);
      acc[c] = n + res[j];
    }
  }

  // lane-local mean/var over the 64 cols this lane owns (4-way ILP chains)
  float s1a = 0.f, s1b = 0.f, s1c = 0.f, s1d = 0.f;
  float s2a = 0.f, s2b = 0.f, s2c = 0.f, s2d = 0.f;
#pragma unroll
  for (int c = 0; c < H; c += 4) {
    s1a += acc[c + 0]; s1b += acc[c + 1]; s1c += acc[c + 2]; s1d += acc[c + 3];
    s2a = fmaf(acc[c + 0], acc[c + 0], s2a);
    s2b = fmaf(acc[c + 1], acc[c + 1], s2b);
    s2c = fmaf(acc[c + 2], acc[c + 2], s2c);
    s2d = fmaf(acc[c + 3], acc[c + 3], s2d);
  }
  const float s1 = (s1a + s1b) + (s1c + s1d);
  const float s2 = (s2a + s2b) + (s2c + s2d);
  const float mean = s1 * (1.0f / 64.0f);
  const float var = s2 * (1.0f / 64.0f) - mean * mean;
  const float rstd = rsqrtf(var + EPS);

  float* po = edges_out + (size_t)e * H;
#pragma unroll
  for (int g = 0; g < 16; ++g) {
    f32v4 o;
    o.x = (acc[g * 4 + 0] - mean) * rstd * ln_s[g * 4 + 0] + ln_b[g * 4 + 0];
    o.y = (acc[g * 4 + 1] - mean) * rstd * ln_s[g * 4 + 1] + ln_b[g * 4 + 1];
    o.z = (acc[g * 4 + 2] - mean) * rstd * ln_s[g * 4 + 2] + ln_b[g * 4 + 2];
    o.w = (acc[g * 4 + 3] - mean) * rstd * ln_s[g * 4 + 3] + ln_b[g * 4 + 3];
    __builtin_nontemporal_store(o, (f32v4*)(po + g * 4));
  }
}

// ---- node kernel: unchanged from round 6 (not the bottleneck, ~30 µs).
// 64 nodes/block, 256 thr, K=128 in 2 phases of 64.
// recv_agg aliases nodes_out: block reads rows [n0,n0+64) during staging
// (all before epilogue stores); per-block row sets disjoint -> race-free.
__global__ __launch_bounds__(256, 3) void node_tiled(
    const float* __restrict__ nodes, const float* recv_agg,
    const float* __restrict__ Wn, const float* __restrict__ bn,
    const float* __restrict__ ln_s, const float* __restrict__ ln_b,
    float* nodes_out) {
  __shared__ __align__(16) float aT[64 * 64];    // 16 KB: [k-k0][n]
  __shared__ __align__(16) float Wb[128 * 64];   // 32 KB
  const int tid = threadIdx.x;
  const int n0 = blockIdx.x * 64;

#pragma unroll
  for (int t = 0; t < 8; ++t) {
    int ci = t * 256 + tid;
    *(float4*)(&Wb[ci * 4]) = *(const float4*)(Wn + ci * 4);
  }

  float acc[4][4];
#pragma unroll
  for (int j = 0; j < 4; ++j)
#pragma unroll
    for (int i = 0; i < 4; ++i) acc[j][i] = 0.0f;

  const int te = (tid >> 4) * 4;
  const int tc = (tid & 15) * 4;

#pragma unroll
  for (int p = 0; p < 2; ++p) {
    const int k0 = 64 * p;
#pragma unroll
    for (int t = 0; t < 4; ++t) {
      int ci = t * 256 + tid;                     // 1024 float4
      int n = ci & 63, kq = ci >> 6;              // kq 0..15
      int kg = k0 + kq * 4;
      int gn = n0 + n;
      int gnc = gn < NN ? gn : NN - 1;
      const float* src = (kg < 64) ? (nodes + (size_t)gnc * H + kg)
                                   : (recv_agg + (size_t)gnc * H + (kg - 64));
      float4 v = *(const float4*)src;
      aT[(kq * 4 + 0) * 64 + n] = v.x;
      aT[(kq * 4 + 1) * 64 + n] = v.y;
      aT[(kq * 4 + 2) * 64 + n] = v.z;
      aT[(kq * 4 + 3) * 64 + n] = v.w;
    }
    __syncthreads();
#pragma unroll 4
    for (int kk = 0; kk < 64; ++kk) {
      float4 a4 = *(const float4*)(&aT[kk * 64 + te]);
      float4 w4 = *(const float4*)(&Wb[(k0 + kk) * 64 + tc]);
      float av[4] = {a4.x, a4.y, a4.z, a4.w};
      float wv[4] = {w4.x, w4.y, w4.z, w4.w};
#pragma unroll
      for (int j = 0; j < 4; ++j)
#pragma unroll
        for (int i = 0; i < 4; ++i) acc[j][i] += av[j] * wv[i];
    }
    __syncthreads();
  }

  const float4 bev = *(const float4*)(bn + tc);
  const float4 sev = *(const float4*)(ln_s + tc);
  const float4 biv = *(const float4*)(ln_b + tc);
#pragma unroll
  for (int j = 0; j < 4; ++j) {
    int gn = n0 + te + j;
    bool valid = gn < NN;
    float4 nv;
    if (valid) nv = *(const float4*)(nodes + (size_t)gn * H + tc);
    else { nv.x = nv.y = nv.z = nv.w = 0.0f; }
    float t0 = acc[j][0] + bev.x + nv.x;
    float t1 = acc[j][1] + bev.y + nv.y;
    float t2 = acc[j][2] + bev.z + nv.z;
    float t3 = acc[j][3] + bev.w + nv.w;
    float s1 = t0 + t1 + t2 + t3;
    float s2 = t0 * t0 + t1 * t1 + t2 * t2 + t3 * t3;
    s1 += __shfl_xor(s1, 1, 64); s2 += __shfl_xor(s2, 1, 64);
    s1 += __shfl_xor(s1, 2, 64); s2 += __shfl_xor(s2, 2, 64);
    s1 += __shfl_xor(s1, 4, 64); s2 += __shfl_xor(s2, 4, 64);
    s1 += __shfl_xor(s1, 8, 64); s2 += __shfl_xor(s2, 8, 64);
    float mean = s1 * (1.0f / 64.0f);
    float var = s2 * (1.0f / 64.0f) - mean * mean;
    float rstd = rsqrtf(var + EPS);
    if (valid) {
      float4 o;
      o.x = (t0 - mean) * rstd * sev.x + biv.x;
      o.y = (t1 - mean) * rstd * sev.y + biv.y;
      o.z = (t2 - mean) * rstd * sev.z + biv.z;
      o.w = (t3 - mean) * rstd * sev.w + biv.w;
      *(float4*)(nodes_out + (size_t)gn * H + tc) = o;
    }
  }
}

extern "C" void kernel_launch(void* const* d_in, const int* in_sizes, int n_in,
                              void* d_out, int out_size, void* d_ws, size_t ws_size,
                              hipStream_t stream) {
  const float* nodes      = (const float*)d_in[0];
  const float* edges      = (const float*)d_in[1];
  const int*   senders    = (const int*)d_in[2];
  const int*   receivers  = (const int*)d_in[3];
  const float* We         = (const float*)d_in[4];
  const float* be         = (const float*)d_in[5];
  const float* Wn         = (const float*)d_in[6];
  const float* bn         = (const float*)d_in[7];
  const float* ln_n_scale = (const float*)d_in[8];
  const float* ln_n_bias  = (const float*)d_in[9];
  const float* ln_e_scale = (const float*)d_in[10];
  const float* ln_e_bias  = (const float*)d_in[11];

  float* out = (float*)d_out;
  float* nodes_out = out;                       // [NN,64]; doubles as recv_agg
  float* edges_out = out + (size_t)NN * H;      // [NE,64]

  (void)hipMemsetAsync(nodes_out, 0, (size_t)NN * H * sizeof(float), stream);
  edge_rowlane<<<(NE + 255) / 256, 256, 0, stream>>>(
      nodes, edges, senders, receivers, We, be, ln_e_scale, ln_e_bias,
      nodes_out, edges_out);
  node_tiled<<<(NN + 63) / 64, 256, 0, stream>>>(nodes, nodes_out, Wn, bn,
                                                 ln_n_scale, ln_n_bias, nodes_out);
}

// Round 2
// 3726.235 us; speedup vs baseline: 1.0284x; 1.0284x over previous
//
#include <hip/hip_runtime.h>

#define H 64
#define NN 100000
#define NE 1000000
#define EPS 1e-6f

// ROUND 8: round-7 lane-per-edge design with the spill fixed.
// Post-mortem of r7: __launch_bounds__(256,4) capped VGPRs at 128; acc[64]
// + 32 staging regs spilled to scratch (VGPR_Count=64, +2.5GB scratch
// writes, +1.1GB scratch reads = the whole 4x regression). Fix: (256,3)
// -> cap ~168 VGPRs, 3 waves/SIMD. Everything else identical: zero LDS,
// W broadcast via scalar loads (SGPR=112 in r7 confirms scalarization),
// lane-local LayerNorm, same atomic pattern (r6 vs r7 counters showed
// atomic HBM cost is count-proportional, pattern-insensitive).

typedef __attribute__((ext_vector_type(4))) float f32v4;

__global__ __launch_bounds__(256, 3) void edge_rowlane(
    const float* __restrict__ nodes, const float* __restrict__ edges,
    const int* __restrict__ senders, const int* __restrict__ receivers,
    const float* __restrict__ We, const float* __restrict__ be,
    const float* __restrict__ ln_s, const float* __restrict__ ln_b,
    float* recv_agg, float* __restrict__ edges_out) {
  const int e = blockIdx.x * 256 + threadIdx.x;
  if (e >= NE) return;  // NE % 64 == 0: exits are whole-wave uniform
  const int s = senders[e];
  const int r = receivers[e];
  const float* pe = edges + (size_t)e * H;
  const float* ps = nodes + (size_t)s * H;
  const float* pr = nodes + (size_t)r * H;

  float acc[H];
#pragma unroll
  for (int c = 0; c < H; ++c) acc[c] = 0.0f;

  // 12 chunks of 16 K-values. Chunk t: region t>>2 (edge/sender/receiver),
  // k-offset (t&3)*16. Each chunk = one 64B line of the source row.
  float4 b0 = *(const float4*)(pe + 0);
  float4 b1 = *(const float4*)(pe + 4);
  float4 b2 = *(const float4*)(pe + 8);
  float4 b3 = *(const float4*)(pe + 12);

#define FMA_ONE(AV, KK)                                                        \
  {                                                                            \
    const float av_ = (AV);                                                    \
    const float* __restrict__ wr_ = wrow + (KK) * H;                           \
    _Pragma("unroll")                                                          \
    for (int c = 0; c < H; ++c) acc[c] = fmaf(wr_[c], av_, acc[c]);            \
  }

#pragma unroll 1  // compact body, dynamic t: I$-friendly, low reg pressure
  for (int t = 0; t < 12; ++t) {
    float4 n0, n1, n2, n3;
    const int tn = t + 1;
    if (tn < 12) {  // prefetch next chunk; latency hides under 1024 FMAs
      const float* src = (tn < 4) ? pe : ((tn < 8) ? ps : pr);
      src += (tn & 3) * 16;
      n0 = *(const float4*)(src + 0);
      n1 = *(const float4*)(src + 4);
      n2 = *(const float4*)(src + 8);
      n3 = *(const float4*)(src + 12);
    }
    // wrow is wave-uniform (t uniform) -> scalar loads -> SGPR operands
    const float* __restrict__ wrow = We + (size_t)t * (16 * H);
    FMA_ONE(b0.x, 0)  FMA_ONE(b0.y, 1)  FMA_ONE(b0.z, 2)  FMA_ONE(b0.w, 3)
    FMA_ONE(b1.x, 4)  FMA_ONE(b1.y, 5)  FMA_ONE(b1.z, 6)  FMA_ONE(b1.w, 7)
    FMA_ONE(b2.x, 8)  FMA_ONE(b2.y, 9)  FMA_ONE(b2.z, 10) FMA_ONE(b2.w, 11)
    FMA_ONE(b3.x, 12) FMA_ONE(b3.y, 13) FMA_ONE(b3.z, 14) FMA_ONE(b3.w, 15)
    if (tn < 12) { b0 = n0; b1 = n1; b2 = n2; b3 = n3; }
  }
#undef FMA_ONE

  // Epilogue: bias -> scatter-add to recv_agg -> residual -> lane-local LN.
  // Residual loads issued at the top of each group so their vmcnt drains
  // without waiting on the 16 fire-and-forget atomics of the group.
  float* ra = recv_agg + (size_t)r * H;
#pragma unroll
  for (int g = 0; g < 4; ++g) {
    const float* pres = pe + g * 16;
    float4 r0 = *(const float4*)(pres + 0);
    float4 r1 = *(const float4*)(pres + 4);
    float4 r2 = *(const float4*)(pres + 8);
    float4 r3 = *(const float4*)(pres + 12);
    const float res[16] = {r0.x, r0.y, r0.z, r0.w, r1.x, r1.y, r1.z, r1.w,
                           r2.x, r2.y, r2.z, r2.w, r3.x, r3.y, r3.z, r3.w};
#pragma unroll
    for (int j = 0; j < 16; ++j) {
      const int c = g * 16 + j;
      const float n = acc[c] + be[c];
      atomicAdd(ra + c, n);
      acc[c] = n + res[j];
    }
  }

  // lane-local mean/var over the 64 cols this lane owns (4-way ILP chains)
  float s1a = 0.f, s1b = 0.f, s1c = 0.f, s1d = 0.f;
  float s2a = 0.f, s2b = 0.f, s2c = 0.f, s2d = 0.f;
#pragma unroll
  for (int c = 0; c < H; c += 4) {
    s1a += acc[c + 0]; s1b += acc[c + 1]; s1c += acc[c + 2]; s1d += acc[c + 3];
    s2a = fmaf(acc[c + 0], acc[c + 0], s2a);
    s2b = fmaf(acc[c + 1], acc[c + 1], s2b);
    s2c = fmaf(acc[c + 2], acc[c + 2], s2c);
    s2d = fmaf(acc[c + 3], acc[c + 3], s2d);
  }
  const float s1 = (s1a + s1b) + (s1c + s1d);
  const float s2 = (s2a + s2b) + (s2c + s2d);
  const float mean = s1 * (1.0f / 64.0f);
  const float var = s2 * (1.0f / 64.0f) - mean * mean;
  const float rstd = rsqrtf(var + EPS);

  float* po = edges_out + (size_t)e * H;
#pragma unroll
  for (int g = 0; g < 16; ++g) {
    f32v4 o;
    o.x = (acc[g * 4 + 0] - mean) * rstd * ln_s[g * 4 + 0] + ln_b[g * 4 + 0];
    o.y = (acc[g * 4 + 1] - mean) * rstd * ln_s[g * 4 + 1] + ln_b[g * 4 + 1];
    o.z = (acc[g * 4 + 2] - mean) * rstd * ln_s[g * 4 + 2] + ln_b[g * 4 + 2];
    o.w = (acc[g * 4 + 3] - mean) * rstd * ln_s[g * 4 + 3] + ln_b[g * 4 + 3];
    __builtin_nontemporal_store(o, (f32v4*)(po + g * 4));
  }
}

// ---- node kernel: unchanged (not the bottleneck, ~30 µs).
// 64 nodes/block, 256 thr, K=128 in 2 phases of 64.
// recv_agg aliases nodes_out: block reads rows [n0,n0+64) during staging
// (all before epilogue stores); per-block row sets disjoint -> race-free.
__global__ __launch_bounds__(256, 3) void node_tiled(
    const float* __restrict__ nodes, const float* recv_agg,
    const float* __restrict__ Wn, const float* __restrict__ bn,
    const float* __restrict__ ln_s, const float* __restrict__ ln_b,
    float* nodes_out) {
  __shared__ __align__(16) float aT[64 * 64];    // 16 KB: [k-k0][n]
  __shared__ __align__(16) float Wb[128 * 64];   // 32 KB
  const int tid = threadIdx.x;
  const int n0 = blockIdx.x * 64;

#pragma unroll
  for (int t = 0; t < 8; ++t) {
    int ci = t * 256 + tid;
    *(float4*)(&Wb[ci * 4]) = *(const float4*)(Wn + ci * 4);
  }

  float acc[4][4];
#pragma unroll
  for (int j = 0; j < 4; ++j)
#pragma unroll
    for (int i = 0; i < 4; ++i) acc[j][i] = 0.0f;

  const int te = (tid >> 4) * 4;
  const int tc = (tid & 15) * 4;

#pragma unroll
  for (int p = 0; p < 2; ++p) {
    const int k0 = 64 * p;
#pragma unroll
    for (int t = 0; t < 4; ++t) {
      int ci = t * 256 + tid;                     // 1024 float4
      int n = ci & 63, kq = ci >> 6;              // kq 0..15
      int kg = k0 + kq * 4;
      int gn = n0 + n;
      int gnc = gn < NN ? gn : NN - 1;
      const float* src = (kg < 64) ? (nodes + (size_t)gnc * H + kg)
                                   : (recv_agg + (size_t)gnc * H + (kg - 64));
      float4 v = *(const float4*)src;
      aT[(kq * 4 + 0) * 64 + n] = v.x;
      aT[(kq * 4 + 1) * 64 + n] = v.y;
      aT[(kq * 4 + 2) * 64 + n] = v.z;
      aT[(kq * 4 + 3) * 64 + n] = v.w;
    }
    __syncthreads();
#pragma unroll 4
    for (int kk = 0; kk < 64; ++kk) {
      float4 a4 = *(const float4*)(&aT[kk * 64 + te]);
      float4 w4 = *(const float4*)(&Wb[(k0 + kk) * 64 + tc]);
      float av[4] = {a4.x, a4.y, a4.z, a4.w};
      float wv[4] = {w4.x, w4.y, w4.z, w4.w};
#pragma unroll
      for (int j = 0; j < 4; ++j)
#pragma unroll
        for (int i = 0; i < 4; ++i) acc[j][i] += av[j] * wv[i];
    }
    __syncthreads();
  }

  const float4 bev = *(const float4*)(bn + tc);
  const float4 sev = *(const float4*)(ln_s + tc);
  const float4 biv = *(const float4*)(ln_b + tc);
#pragma unroll
  for (int j = 0; j < 4; ++j) {
    int gn = n0 + te + j;
    bool valid = gn < NN;
    float4 nv;
    if (valid) nv = *(const float4*)(nodes + (size_t)gn * H + tc);
    else { nv.x = nv.y = nv.z = nv.w = 0.0f; }
    float t0 = acc[j][0] + bev.x + nv.x;
    float t1 = acc[j][1] + bev.y + nv.y;
    float t2 = acc[j][2] + bev.z + nv.z;
    float t3 = acc[j][3] + bev.w + nv.w;
    float s1 = t0 + t1 + t2 + t3;
    float s2 = t0 * t0 + t1 * t1 + t2 * t2 + t3 * t3;
    s1 += __shfl_xor(s1, 1, 64); s2 += __shfl_xor(s2, 1, 64);
    s1 += __shfl_xor(s1, 2, 64); s2 += __shfl_xor(s2, 2, 64);
    s1 += __shfl_xor(s1, 4, 64); s2 += __shfl_xor(s2, 4, 64);
    s1 += __shfl_xor(s1, 8, 64); s2 += __shfl_xor(s2, 8, 64);
    float mean = s1 * (1.0f / 64.0f);
    float var = s2 * (1.0f / 64.0f) - mean * mean;
    float rstd = rsqrtf(var + EPS);
    if (valid) {
      float4 o;
      o.x = (t0 - mean) * rstd * sev.x + biv.x;
      o.y = (t1 - mean) * rstd * sev.y + biv.y;
      o.z = (t2 - mean) * rstd * sev.z + biv.z;
      o.w = (t3 - mean) * rstd * sev.w + biv.w;
      *(float4*)(nodes_out + (size_t)gn * H + tc) = o;
    }
  }
}

extern "C" void kernel_launch(void* const* d_in, const int* in_sizes, int n_in,
                              void* d_out, int out_size, void* d_ws, size_t ws_size,
                              hipStream_t stream) {
  const float* nodes      = (const float*)d_in[0];
  const float* edges      = (const float*)d_in[1];
  const int*   senders    = (const int*)d_in[2];
  const int*   receivers  = (const int*)d_in[3];
  const float* We         = (const float*)d_in[4];
  const float* be         = (const float*)d_in[5];
  const float* Wn         = (const float*)d_in[6];
  const float* bn         = (const float*)d_in[7];
  const float* ln_n_scale = (const float*)d_in[8];
  const float* ln_n_bias  = (const float*)d_in[9];
  const float* ln_e_scale = (const float*)d_in[10];
  const float* ln_e_bias  = (const float*)d_in[11];

  float* out = (float*)d_out;
  float* nodes_out = out;                       // [NN,64]; doubles as recv_agg
  float* edges_out = out + (size_t)NN * H;      // [NE,64]

  (void)hipMemsetAsync(nodes_out, 0, (size_t)NN * H * sizeof(float), stream);
  edge_rowlane<<<(NE + 255) / 256, 256, 0, stream>>>(
      nodes, edges, senders, receivers, We, be, ln_e_scale, ln_e_bias,
      nodes_out, edges_out);
  node_tiled<<<(NN + 63) / 64, 256, 0, stream>>>(nodes, nodes_out, Wn, bn,
                                                 ln_n_scale, ln_n_bias, nodes_out);
}

// Round 3
// 3588.438 us; speedup vs baseline: 1.0678x; 1.0384x over previous
//
#include <hip/hip_runtime.h>

#define H 64
#define NN 100000
#define NE 1000000
#define EPS 1e-6f

// ROUND 9: lane-per-edge, zero LDS, W on the scalar pipe -- but the output
// row is computed in TWO COLUMN HALVES (acc[32] each) to stay far below the
// register cliff. r7 ((256,4): VGPR=64 + 2.5GB scratch) and r8 ((256,3):
// VGPR=76 + 1.4GB scratch) proved acc[64]+staging doesn't fit no matter the
// cap. Pass 1: cols 0-31, atomics, raw pre-LN store to edges_out (scratch).
// Pass 2: cols 32-63, atomics, finish s1/s2, LN own cols, volatile-reload
// pass-1 raws (L2-hot; volatile blocks forwarding so they don't stay live
// through pass 2), LN, store. K-inputs re-read once (L2-hot, ~free on the
// 34TB/s L2). FMA count unchanged -> VALU floor 156us.

typedef __attribute__((ext_vector_type(4))) float f32v4;

__global__ __launch_bounds__(256, 4) void edge_half(
    const float* __restrict__ nodes, const float* __restrict__ edges,
    const int* __restrict__ senders, const int* __restrict__ receivers,
    const float* __restrict__ We, const float* __restrict__ be,
    const float* __restrict__ ln_s, const float* __restrict__ ln_b,
    float* recv_agg, float* __restrict__ edges_out) {
  const int e = blockIdx.x * 256 + threadIdx.x;
  if (e >= NE) return;  // NE % 64 == 0: exits are whole-wave uniform
  const int s = senders[e];
  const int r = receivers[e];
  const float* pe = edges + (size_t)e * H;
  const float* ps = nodes + (size_t)s * H;
  const float* pr = nodes + (size_t)r * H;
  float* ra = recv_agg + (size_t)r * H;
  float* po = edges_out + (size_t)e * H;

  float s1 = 0.f, s2 = 0.f;
  float acc[32];

#define FMA_K(AV, KK)                                                          \
  {                                                                            \
    const float av_ = (AV);                                                    \
    _Pragma("unroll")                                                          \
    for (int c = 0; c < 32; ++c)                                               \
      acc[c] = fmaf(wr[(KK) * 64 + c], av_, acc[c]);                           \
  }

#pragma unroll
  for (int hh = 0; hh < 2; ++hh) {
    const int c0 = hh * 32;
#pragma unroll
    for (int c = 0; c < 32; ++c) acc[c] = 0.f;

    // 12 chunks of 16 K-values; chunk t: region t>>2, k-offset (t&3)*16.
    float4 b0 = *(const float4*)(pe + 0);
    float4 b1 = *(const float4*)(pe + 4);
    float4 b2 = *(const float4*)(pe + 8);
    float4 b3 = *(const float4*)(pe + 12);

#pragma unroll 1  // compact body, dynamic t: low reg pressure, I$-friendly
    for (int t = 0; t < 12; ++t) {
      float4 n0, n1, n2, n3;
      const int tn = t + 1;
      if (tn < 12) {  // prefetch next 64B line; hides under 512 FMAs
        const float* src = (tn < 4) ? pe : ((tn < 8) ? ps : pr);
        src += (tn & 3) * 16;
        n0 = *(const float4*)(src + 0);
        n1 = *(const float4*)(src + 4);
        n2 = *(const float4*)(src + 8);
        n3 = *(const float4*)(src + 12);
      }
      // wr is wave-uniform -> s_load -> SGPR broadcast operand of v_fmac
      const float* __restrict__ wr = We + (size_t)t * (16 * H) + c0;
      FMA_K(b0.x, 0)  FMA_K(b0.y, 1)  FMA_K(b0.z, 2)  FMA_K(b0.w, 3)
      FMA_K(b1.x, 4)  FMA_K(b1.y, 5)  FMA_K(b1.z, 6)  FMA_K(b1.w, 7)
      FMA_K(b2.x, 8)  FMA_K(b2.y, 9)  FMA_K(b2.z, 10) FMA_K(b2.w, 11)
      FMA_K(b3.x, 12) FMA_K(b3.y, 13) FMA_K(b3.z, 14) FMA_K(b3.w, 15)
      if (tn < 12) { b0 = n0; b1 = n1; b2 = n2; b3 = n3; }
    }

    // half-epilogue: bias -> scatter-add -> +residual -> partial LN sums
    const float* pres = pe + c0;
#pragma unroll
    for (int q = 0; q < 8; ++q) {
      const float4 bv = *(const float4*)(be + c0 + q * 4);
      const float4 rv = *(const float4*)(pres + q * 4);
      const float bb[4] = {bv.x, bv.y, bv.z, bv.w};
      const float rr[4] = {rv.x, rv.y, rv.z, rv.w};
#pragma unroll
      for (int j = 0; j < 4; ++j) {
        const int c = q * 4 + j;
        const float n = acc[c] + bb[j];
        atomicAdd(ra + c0 + c, n);
        acc[c] = n + rr[j];
      }
    }
    // 4-way ILP partial sums
    {
      float a0 = 0.f, a1 = 0.f, a2 = 0.f, a3 = 0.f;
      float q0 = 0.f, q1 = 0.f, q2 = 0.f, q3 = 0.f;
#pragma unroll
      for (int c = 0; c < 32; c += 4) {
        a0 += acc[c + 0]; a1 += acc[c + 1]; a2 += acc[c + 2]; a3 += acc[c + 3];
        q0 = fmaf(acc[c + 0], acc[c + 0], q0);
        q1 = fmaf(acc[c + 1], acc[c + 1], q1);
        q2 = fmaf(acc[c + 2], acc[c + 2], q2);
        q3 = fmaf(acc[c + 3], acc[c + 3], q3);
      }
      s1 += (a0 + a1) + (a2 + a3);
      s2 += (q0 + q1) + (q2 + q3);
    }

    if (hh == 0) {
      // stash raw pre-LN cols 0..31 in edges_out (rewritten below); plain
      // stores -- these WILL be reloaded, keep them cacheable.
#pragma unroll
      for (int q = 0; q < 8; ++q) {
        f32v4 v;
        v.x = acc[q * 4 + 0]; v.y = acc[q * 4 + 1];
        v.z = acc[q * 4 + 2]; v.w = acc[q * 4 + 3];
        *(f32v4*)(po + q * 4) = v;
      }
    }
  }
#undef FMA_K

  const float mean = s1 * (1.0f / 64.0f);
  const float var = s2 * (1.0f / 64.0f) - mean * mean;
  const float rstd = rsqrtf(var + EPS);

  // LN cols 32..63 (still in acc) -> final store
#pragma unroll
  for (int q = 0; q < 8; ++q) {
    const int c = 32 + q * 4;
    f32v4 o;
    o.x = (acc[q * 4 + 0] - mean) * rstd * ln_s[c + 0] + ln_b[c + 0];
    o.y = (acc[q * 4 + 1] - mean) * rstd * ln_s[c + 1] + ln_b[c + 1];
    o.z = (acc[q * 4 + 2] - mean) * rstd * ln_s[c + 2] + ln_b[c + 2];
    o.w = (acc[q * 4 + 3] - mean) * rstd * ln_s[c + 3] + ln_b[c + 3];
    __builtin_nontemporal_store(o, (f32v4*)(po + c));
  }
  // volatile-reload raw cols 0..31 (L2-hot, just written by this thread),
  // LN, final store. volatile forbids store->load forwarding, so these 32
  // values are NOT kept live across pass 2 by the compiler.
#pragma unroll
  for (int q = 0; q < 8; ++q) {
    const int c = q * 4;
    const f32v4 tv = *(const volatile f32v4*)(po + c);
    f32v4 o;
    o.x = (tv.x - mean) * rstd * ln_s[c + 0] + ln_b[c + 0];
    o.y = (tv.y - mean) * rstd * ln_s[c + 1] + ln_b[c + 1];
    o.z = (tv.z - mean) * rstd * ln_s[c + 2] + ln_b[c + 2];
    o.w = (tv.w - mean) * rstd * ln_s[c + 3] + ln_b[c + 3];
    __builtin_nontemporal_store(o, (f32v4*)(po + c));
  }
}

// ---- node kernel: unchanged (not the bottleneck, ~30 µs).
// 64 nodes/block, 256 thr, K=128 in 2 phases of 64.
// recv_agg aliases nodes_out: block reads rows [n0,n0+64) during staging
// (all before epilogue stores); per-block row sets disjoint -> race-free.
__global__ __launch_bounds__(256, 3) void node_tiled(
    const float* __restrict__ nodes, const float* recv_agg,
    const float* __restrict__ Wn, const float* __restrict__ bn,
    const float* __restrict__ ln_s, const float* __restrict__ ln_b,
    float* nodes_out) {
  __shared__ __align__(16) float aT[64 * 64];    // 16 KB: [k-k0][n]
  __shared__ __align__(16) float Wb[128 * 64];   // 32 KB
  const int tid = threadIdx.x;
  const int n0 = blockIdx.x * 64;

#pragma unroll
  for (int t = 0; t < 8; ++t) {
    int ci = t * 256 + tid;
    *(float4*)(&Wb[ci * 4]) = *(const float4*)(Wn + ci * 4);
  }

  float acc[4][4];
#pragma unroll
  for (int j = 0; j < 4; ++j)
#pragma unroll
    for (int i = 0; i < 4; ++i) acc[j][i] = 0.0f;

  const int te = (tid >> 4) * 4;
  const int tc = (tid & 15) * 4;

#pragma unroll
  for (int p = 0; p < 2; ++p) {
    const int k0 = 64 * p;
#pragma unroll
    for (int t = 0; t < 4; ++t) {
      int ci = t * 256 + tid;                     // 1024 float4
      int n = ci & 63, kq = ci >> 6;              // kq 0..15
      int kg = k0 + kq * 4;
      int gn = n0 + n;
      int gnc = gn < NN ? gn : NN - 1;
      const float* src = (kg < 64) ? (nodes + (size_t)gnc * H + kg)
                                   : (recv_agg + (size_t)gnc * H + (kg - 64));
      float4 v = *(const float4*)src;
      aT[(kq * 4 + 0) * 64 + n] = v.x;
      aT[(kq * 4 + 1) * 64 + n] = v.y;
      aT[(kq * 4 + 2) * 64 + n] = v.z;
      aT[(kq * 4 + 3) * 64 + n] = v.w;
    }
    __syncthreads();
#pragma unroll 4
    for (int kk = 0; kk < 64; ++kk) {
      float4 a4 = *(const float4*)(&aT[kk * 64 + te]);
      float4 w4 = *(const float4*)(&Wb[(k0 + kk) * 64 + tc]);
      float av[4] = {a4.x, a4.y, a4.z, a4.w};
      float wv[4] = {w4.x, w4.y, w4.z, w4.w};
#pragma unroll
      for (int j = 0; j < 4; ++j)
#pragma unroll
        for (int i = 0; i < 4; ++i) acc[j][i] += av[j] * wv[i];
    }
    __syncthreads();
  }

  const float4 bev = *(const float4*)(bn + tc);
  const float4 sev = *(const float4*)(ln_s + tc);
  const float4 biv = *(const float4*)(ln_b + tc);
#pragma unroll
  for (int j = 0; j < 4; ++j) {
    int gn = n0 + te + j;
    bool valid = gn < NN;
    float4 nv;
    if (valid) nv = *(const float4*)(nodes + (size_t)gn * H + tc);
    else { nv.x = nv.y = nv.z = nv.w = 0.0f; }
    float t0 = acc[j][0] + bev.x + nv.x;
    float t1 = acc[j][1] + bev.y + nv.y;
    float t2 = acc[j][2] + bev.z + nv.z;
    float t3 = acc[j][3] + bev.w + nv.w;
    float s1 = t0 + t1 + t2 + t3;
    float s2 = t0 * t0 + t1 * t1 + t2 * t2 + t3 * t3;
    s1 += __shfl_xor(s1, 1, 64); s2 += __shfl_xor(s2, 1, 64);
    s1 += __shfl_xor(s1, 2, 64); s2 += __shfl_xor(s2, 2, 64);
    s1 += __shfl_xor(s1, 4, 64); s2 += __shfl_xor(s2, 4, 64);
    s1 += __shfl_xor(s1, 8, 64); s2 += __shfl_xor(s2, 8, 64);
    float mean = s1 * (1.0f / 64.0f);
    float var = s2 * (1.0f / 64.0f) - mean * mean;
    float rstd = rsqrtf(var + EPS);
    if (valid) {
      float4 o;
      o.x = (t0 - mean) * rstd * sev.x + biv.x;
      o.y = (t1 - mean) * rstd * sev.y + biv.y;
      o.z = (t2 - mean) * rstd * sev.z + biv.z;
      o.w = (t3 - mean) * rstd * sev.w + biv.w;
      *(float4*)(nodes_out + (size_t)gn * H + tc) = o;
    }
  }
}

extern "C" void kernel_launch(void* const* d_in, const int* in_sizes, int n_in,
                              void* d_out, int out_size, void* d_ws, size_t ws_size,
                              hipStream_t stream) {
  const float* nodes      = (const float*)d_in[0];
  const float* edges      = (const float*)d_in[1];
  const int*   senders    = (const int*)d_in[2];
  const int*   receivers  = (const int*)d_in[3];
  const float* We         = (const float*)d_in[4];
  const float* be         = (const float*)d_in[5];
  const float* Wn         = (const float*)d_in[6];
  const float* bn         = (const float*)d_in[7];
  const float* ln_n_scale = (const float*)d_in[8];
  const float* ln_n_bias  = (const float*)d_in[9];
  const float* ln_e_scale = (const float*)d_in[10];
  const float* ln_e_bias  = (const float*)d_in[11];

  float* out = (float*)d_out;
  float* nodes_out = out;                       // [NN,64]; doubles as recv_agg
  float* edges_out = out + (size_t)NN * H;      // [NE,64]

  (void)hipMemsetAsync(nodes_out, 0, (size_t)NN * H * sizeof(float), stream);
  edge_half<<<(NE + 255) / 256, 256, 0, stream>>>(
      nodes, edges, senders, receivers, We, be, ln_e_scale, ln_e_bias,
      nodes_out, edges_out);
  node_tiled<<<(NN + 63) / 64, 256, 0, stream>>>(nodes, nodes_out, Wn, bn,
                                                 ln_n_scale, ln_n_bias, nodes_out);
}

// Round 4
// 3585.918 us; speedup vs baseline: 1.0686x; 1.0007x over previous
//
#include <hip/hip_runtime.h>

#define H 64
#define NN 100000
#define NE 1000000
#define EPS 1e-6f

// ROUND 10: wave-per-column-slice. r7-r9 post-mortems: per-lane full-row
// layouts spill because the W operand's staged live ranges explode (512
// floats hoisted against ~200cy latency), independent of acc size. Fix by
// layout: block = 64 edges, 4 waves; wave w owns cols [16w,16w+16); lane =
// edge. W addressing depends only on (t, wave-id) -- forced wave-uniform
// via readfirstlane -> s_load -> SGPR broadcast operand of v_fmac, zero
// VGPR cost at use. acc[16] + 32 staging regs ~= 70 VGPR, half the (256,4)
// cap: spill impossible by construction. A rows re-read by the block's 4
// waves hit L1. LN: 2KB-LDS cross-wave s1/s2 reduce, one barrier.
// Diagnostic branch: if this lands ~850us with clean writes + low VALU,
// the 64M-atomic TCC rate (~29/cy in r6) is the wall -> CSR next.

__global__ __launch_bounds__(256, 4) void edge_slice(
    const float* __restrict__ nodes, const float* __restrict__ edges,
    const int* __restrict__ senders, const int* __restrict__ receivers,
    const float* __restrict__ We, const float* __restrict__ be,
    const float* __restrict__ ln_s, const float* __restrict__ ln_b,
    float* recv_agg, float* __restrict__ edges_out) {
  __shared__ float sm1[4][64];
  __shared__ float sm2[4][64];
  const int lane = threadIdx.x & 63;
  const int wv = __builtin_amdgcn_readfirstlane(threadIdx.x >> 6);  // 0..3
  const int c0 = wv * 16;                 // SGPR: all W/param addressing
  const int e = blockIdx.x * 64 + lane;   // grid exact: NE % 64 == 0
  const int s = senders[e];
  const int r = receivers[e];
  const float* pe = edges + (size_t)e * H;
  const float* ps = nodes + (size_t)s * H;
  const float* pr = nodes + (size_t)r * H;

  float acc[16];
#pragma unroll
  for (int c = 0; c < 16; ++c) acc[c] = 0.f;

  // A: 12 chunks of 16 K-values; chunk t: region t>>2 (edge/sender/recv),
  // k-offset (t&3)*16 -- one 64B line per chunk, prefetched one ahead.
  float4 b0 = *(const float4*)(pe + 0);
  float4 b1 = *(const float4*)(pe + 4);
  float4 b2 = *(const float4*)(pe + 8);
  float4 b3 = *(const float4*)(pe + 12);

#define FMA_K(AV, KK)                                                          \
  {                                                                            \
    const float av_ = (AV);                                                    \
    _Pragma("unroll")                                                          \
    for (int c = 0; c < 16; ++c)                                               \
      acc[c] = fmaf(wbase[(KK) * 64 + c], av_, acc[c]);                        \
  }

#pragma unroll 1  // dynamic t: compact body, bounded SGPR live ranges
  for (int t = 0; t < 12; ++t) {
    float4 n0, n1, n2, n3;
    const int tn = t + 1;
    if (tn < 12) {  // prefetch next 64B line; hides under 256 FMAs
      const float* src = (tn < 4) ? pe : ((tn < 8) ? ps : pr);
      src += (tn & 3) * 16;
      n0 = *(const float4*)(src + 0);
      n1 = *(const float4*)(src + 4);
      n2 = *(const float4*)(src + 8);
      n3 = *(const float4*)(src + 12);
    }
    // wbase: uniform (We + t + wave-slice) -> s_load_dwordx16 per k-row
    const float* __restrict__ wbase = We + (size_t)t * (16 * H) + c0;
    FMA_K(b0.x, 0)  FMA_K(b0.y, 1)  FMA_K(b0.z, 2)  FMA_K(b0.w, 3)
    FMA_K(b1.x, 4)  FMA_K(b1.y, 5)  FMA_K(b1.z, 6)  FMA_K(b1.w, 7)
    FMA_K(b2.x, 8)  FMA_K(b2.y, 9)  FMA_K(b2.z, 10) FMA_K(b2.w, 11)
    FMA_K(b3.x, 12) FMA_K(b3.y, 13) FMA_K(b3.z, 14) FMA_K(b3.w, 15)
    if (tn < 12) { b0 = n0; b1 = n1; b2 = n2; b3 = n3; }
  }
#undef FMA_K

  // Epilogue. Residual loads issued BEFORE the atomics so their vmcnt
  // drains without queueing behind atomic acks. pe cols c0.. are L1-hot
  // (they were A-chunk wv of region 0).
  float4 r0v = *(const float4*)(pe + c0 + 0);
  float4 r1v = *(const float4*)(pe + c0 + 4);
  float4 r2v = *(const float4*)(pe + c0 + 8);
  float4 r3v = *(const float4*)(pe + c0 + 12);
  const float res[16] = {r0v.x, r0v.y, r0v.z, r0v.w, r1v.x, r1v.y, r1v.z,
                         r1v.w, r2v.x, r2v.y, r2v.z, r2v.w, r3v.x, r3v.y,
                         r3v.z, r3v.w};
  float* ra = recv_agg + (size_t)r * H + c0;
#pragma unroll
  for (int j = 0; j < 16; ++j) {
    const float n = acc[j] + be[c0 + j];  // be[c0+j]: uniform -> s_load
    atomicAdd(ra + j, n);
    acc[j] = n + res[j];
  }

  // partial LN sums (4-way ILP), cross-wave reduce via 2KB LDS
  {
    float a0 = 0.f, a1 = 0.f, a2 = 0.f, a3 = 0.f;
    float q0 = 0.f, q1 = 0.f, q2 = 0.f, q3 = 0.f;
#pragma unroll
    for (int c = 0; c < 16; c += 4) {
      a0 += acc[c + 0]; a1 += acc[c + 1]; a2 += acc[c + 2]; a3 += acc[c + 3];
      q0 = fmaf(acc[c + 0], acc[c + 0], q0);
      q1 = fmaf(acc[c + 1], acc[c + 1], q1);
      q2 = fmaf(acc[c + 2], acc[c + 2], q2);
      q3 = fmaf(acc[c + 3], acc[c + 3], q3);
    }
    sm1[wv][lane] = (a0 + a1) + (a2 + a3);
    sm2[wv][lane] = (q0 + q1) + (q2 + q3);
  }
  __syncthreads();
  const float s1 = (sm1[0][lane] + sm1[1][lane]) + (sm1[2][lane] + sm1[3][lane]);
  const float s2 = (sm2[0][lane] + sm2[1][lane]) + (sm2[2][lane] + sm2[3][lane]);
  const float mean = s1 * (1.0f / 64.0f);
  const float var = s2 * (1.0f / 64.0f) - mean * mean;
  const float rstd = rsqrtf(var + EPS);

  // LN own 16 cols -> plain stores (lane-strided 16B chunks; L2 combines,
  // so no nontemporal hint here)
  float* po = edges_out + (size_t)e * H + c0;
#pragma unroll
  for (int q = 0; q < 4; ++q) {
    const int c = q * 4;
    float4 o;
    o.x = (acc[c + 0] - mean) * rstd * ln_s[c0 + c + 0] + ln_b[c0 + c + 0];
    o.y = (acc[c + 1] - mean) * rstd * ln_s[c0 + c + 1] + ln_b[c0 + c + 1];
    o.z = (acc[c + 2] - mean) * rstd * ln_s[c0 + c + 2] + ln_b[c0 + c + 2];
    o.w = (acc[c + 3] - mean) * rstd * ln_s[c0 + c + 3] + ln_b[c0 + c + 3];
    *(float4*)(po + c) = o;
  }
}

// ---- node kernel: unchanged (not the bottleneck, ~30 µs).
// 64 nodes/block, 256 thr, K=128 in 2 phases of 64.
// recv_agg aliases nodes_out: block reads rows [n0,n0+64) during staging
// (all before epilogue stores); per-block row sets disjoint -> race-free.
__global__ __launch_bounds__(256, 3) void node_tiled(
    const float* __restrict__ nodes, const float* recv_agg,
    const float* __restrict__ Wn, const float* __restrict__ bn,
    const float* __restrict__ ln_s, const float* __restrict__ ln_b,
    float* nodes_out) {
  __shared__ __align__(16) float aT[64 * 64];    // 16 KB: [k-k0][n]
  __shared__ __align__(16) float Wb[128 * 64];   // 32 KB
  const int tid = threadIdx.x;
  const int n0 = blockIdx.x * 64;

#pragma unroll
  for (int t = 0; t < 8; ++t) {
    int ci = t * 256 + tid;
    *(float4*)(&Wb[ci * 4]) = *(const float4*)(Wn + ci * 4);
  }

  float acc[4][4];
#pragma unroll
  for (int j = 0; j < 4; ++j)
#pragma unroll
    for (int i = 0; i < 4; ++i) acc[j][i] = 0.0f;

  const int te = (tid >> 4) * 4;
  const int tc = (tid & 15) * 4;

#pragma unroll
  for (int p = 0; p < 2; ++p) {
    const int k0 = 64 * p;
#pragma unroll
    for (int t = 0; t < 4; ++t) {
      int ci = t * 256 + tid;                     // 1024 float4
      int n = ci & 63, kq = ci >> 6;              // kq 0..15
      int kg = k0 + kq * 4;
      int gn = n0 + n;
      int gnc = gn < NN ? gn : NN - 1;
      const float* src = (kg < 64) ? (nodes + (size_t)gnc * H + kg)
                                   : (recv_agg + (size_t)gnc * H + (kg - 64));
      float4 v = *(const float4*)src;
      aT[(kq * 4 + 0) * 64 + n] = v.x;
      aT[(kq * 4 + 1) * 64 + n] = v.y;
      aT[(kq * 4 + 2) * 64 + n] = v.z;
      aT[(kq * 4 + 3) * 64 + n] = v.w;
    }
    __syncthreads();
#pragma unroll 4
    for (int kk = 0; kk < 64; ++kk) {
      float4 a4 = *(const float4*)(&aT[kk * 64 + te]);
      float4 w4 = *(const float4*)(&Wb[(k0 + kk) * 64 + tc]);
      float av[4] = {a4.x, a4.y, a4.z, a4.w};
      float wv[4] = {w4.x, w4.y, w4.z, w4.w};
#pragma unroll
      for (int j = 0; j < 4; ++j)
#pragma unroll
        for (int i = 0; i < 4; ++i) acc[j][i] += av[j] * wv[i];
    }
    __syncthreads();
  }

  const float4 bev = *(const float4*)(bn + tc);
  const float4 sev = *(const float4*)(ln_s + tc);
  const float4 biv = *(const float4*)(ln_b + tc);
#pragma unroll
  for (int j = 0; j < 4; ++j) {
    int gn = n0 + te + j;
    bool valid = gn < NN;
    float4 nv;
    if (valid) nv = *(const float4*)(nodes + (size_t)gn * H + tc);
    else { nv.x = nv.y = nv.z = nv.w = 0.0f; }
    float t0 = acc[j][0] + bev.x + nv.x;
    float t1 = acc[j][1] + bev.y + nv.y;
    float t2 = acc[j][2] + bev.z + nv.z;
    float t3 = acc[j][3] + bev.w + nv.w;
    float s1 = t0 + t1 + t2 + t3;
    float s2 = t0 * t0 + t1 * t1 + t2 * t2 + t3 * t3;
    s1 += __shfl_xor(s1, 1, 64); s2 += __shfl_xor(s2, 1, 64);
    s1 += __shfl_xor(s1, 2, 64); s2 += __shfl_xor(s2, 2, 64);
    s1 += __shfl_xor(s1, 4, 64); s2 += __shfl_xor(s2, 4, 64);
    s1 += __shfl_xor(s1, 8, 64); s2 += __shfl_xor(s2, 8, 64);
    float mean = s1 * (1.0f / 64.0f);
    float var = s2 * (1.0f / 64.0f) - mean * mean;
    float rstd = rsqrtf(var + EPS);
    if (valid) {
      float4 o;
      o.x = (t0 - mean) * rstd * sev.x + biv.x;
      o.y = (t1 - mean) * rstd * sev.y + biv.y;
      o.z = (t2 - mean) * rstd * sev.z + biv.z;
      o.w = (t3 - mean) * rstd * sev.w + biv.w;
      *(float4*)(nodes_out + (size_t)gn * H + tc) = o;
    }
  }
}

extern "C" void kernel_launch(void* const* d_in, const int* in_sizes, int n_in,
                              void* d_out, int out_size, void* d_ws, size_t ws_size,
                              hipStream_t stream) {
  const float* nodes      = (const float*)d_in[0];
  const float* edges      = (const float*)d_in[1];
  const int*   senders    = (const int*)d_in[2];
  const int*   receivers  = (const int*)d_in[3];
  const float* We         = (const float*)d_in[4];
  const float* be         = (const float*)d_in[5];
  const float* Wn         = (const float*)d_in[6];
  const float* bn         = (const float*)d_in[7];
  const float* ln_n_scale = (const float*)d_in[8];
  const float* ln_n_bias  = (const float*)d_in[9];
  const float* ln_e_scale = (const float*)d_in[10];
  const float* ln_e_bias  = (const float*)d_in[11];

  float* out = (float*)d_out;
  float* nodes_out = out;                       // [NN,64]; doubles as recv_agg
  float* edges_out = out + (size_t)NN * H;      // [NE,64]

  (void)hipMemsetAsync(nodes_out, 0, (size_t)NN * H * sizeof(float), stream);
  edge_slice<<<NE / 64, 256, 0, stream>>>(
      nodes, edges, senders, receivers, We, be, ln_e_scale, ln_e_bias,
      nodes_out, edges_out);
  node_tiled<<<(NN + 63) / 64, 256, 0, stream>>>(nodes, nodes_out, Wn, bn,
                                                 ln_n_scale, ln_n_bias, nodes_out);
}

// Round 5
// 1897.952 us; speedup vs baseline: 2.0190x; 1.8894x over previous
//
#include <hip/hip_runtime.h>

#define H 64
#define NN 100000
#define NE 1000000
#define EPS 1e-6f

// ROUND 11: return to the proven r6 tiled structure (924us) and fix its
// measured bottleneck (shared LDS pipe ~3x oversubscribed: 2 b128 per 16
// FMA per thread -> VALUBusy capped ~25%). r8/r9/r10 (W streamed per-wave
// from memory) all plateaued at 3.5ms/20% VALU -- W staging through
// SGPR/VGPR live ranges is a dead end; W belongs in LDS, read-broadcast.
// Changes vs r6:
//  - 8x8 register blocking (256 edges x 64 cols per block): 64B LDS per 64
//    FMA = 1 B/FMA (r6: 2 B/FMA), and every A/W read is 8-way broadcast.
//  - W (192x64, 48KB) staged ONCE per block; A in 12 region-aligned phases
//    of K=16 (thread loads 64B of its OWN edge row; transpose writes are
//    bank-conflict-free: bank = tid%32).
//  - VGPR ~100 (64 acc + operands) under the (256,4) cap: no spill.
// Diagnostic: if this lands ~880us with clean writes + low VALU, the 64M
// atomic rate is the wall -> CSR next round.

__global__ __launch_bounds__(256, 4) void edge_rb8(
    const float* __restrict__ nodes, const float* __restrict__ edges,
    const int* __restrict__ senders, const int* __restrict__ receivers,
    const float* __restrict__ We, const float* __restrict__ be,
    const float* __restrict__ ln_s, const float* __restrict__ ln_b,
    float* recv_agg, float* __restrict__ edges_out) {
  __shared__ __align__(16) float Wb[192 * 64];  // 48 KB, staged once
  __shared__ __align__(16) float aT[16 * 256];  // 16 KB, [k][edge] per phase
  __shared__ int rBlk[256];
  const int tid = threadIdx.x;
  const int e0 = blockIdx.x * 256;
  const int myE = e0 + tid;
  const int eC = myE < NE ? myE : NE - 1;   // clamped: loads only
  const int sIdx = senders[eC];
  const int rIdx = receivers[eC];
  rBlk[tid] = rIdx;

  // stage all of We (row-major [192][64] -> same layout, coalesced)
#pragma unroll
  for (int t = 0; t < 12; ++t) {
    const int ci = t * 256 + tid;
    *(float4*)(&Wb[ci * 4]) = *(const float4*)(We + (size_t)ci * 4);
  }

  float acc[8][8];
#pragma unroll
  for (int j = 0; j < 8; ++j)
#pragma unroll
    for (int i = 0; i < 8; ++i) acc[j][i] = 0.0f;

  const int te = (tid >> 3) * 8;   // 32 groups x 8 edges
  const int tc = (tid & 7) * 8;    // 8 groups x 8 cols

  // 12 phases of K=16; phase p region: p<4 edges, p<8 sender, else receiver
  // (regions are 64-wide = 4 phases each -> region uniform per phase).
#pragma unroll 1
  for (int p = 0; p < 12; ++p) {
    const float* src;
    if (p < 4)       src = edges + (size_t)eC * H + p * 16;
    else if (p < 8)  src = nodes + (size_t)sIdx * H + (p - 4) * 16;
    else             src = nodes + (size_t)rIdx * H + (p - 8) * 16;
    // 64B contiguous of this thread's own edge row (L1-hot across phases)
    float4 v0 = *(const float4*)(src + 0);
    float4 v1 = *(const float4*)(src + 4);
    float4 v2 = *(const float4*)(src + 8);
    float4 v3 = *(const float4*)(src + 12);
    __syncthreads();   // previous phase's compute done reading aT
    // transpose write: aT[k][e=tid]; bank = (k*256+tid)%32 = tid%32: clean
    aT[0 * 256 + tid] = v0.x;  aT[1 * 256 + tid] = v0.y;
    aT[2 * 256 + tid] = v0.z;  aT[3 * 256 + tid] = v0.w;
    aT[4 * 256 + tid] = v1.x;  aT[5 * 256 + tid] = v1.y;
    aT[6 * 256 + tid] = v1.z;  aT[7 * 256 + tid] = v1.w;
    aT[8 * 256 + tid] = v2.x;  aT[9 * 256 + tid] = v2.y;
    aT[10 * 256 + tid] = v2.z; aT[11 * 256 + tid] = v2.w;
    aT[12 * 256 + tid] = v3.x; aT[13 * 256 + tid] = v3.y;
    aT[14 * 256 + tid] = v3.z; aT[15 * 256 + tid] = v3.w;
    __syncthreads();
    const float* __restrict__ wp = Wb + (size_t)p * 16 * 64;
#pragma unroll 4
    for (int kk = 0; kk < 16; ++kk) {
      // A: 8 edges at fixed k (8-way broadcast across lanes)
      float4 a0 = *(const float4*)(&aT[kk * 256 + te + 0]);
      float4 a1 = *(const float4*)(&aT[kk * 256 + te + 4]);
      // W: 8 cols at fixed k (8-way broadcast across lanes)
      float4 w0 = *(const float4*)(&wp[kk * 64 + tc + 0]);
      float4 w1 = *(const float4*)(&wp[kk * 64 + tc + 4]);
      const float av[8] = {a0.x, a0.y, a0.z, a0.w, a1.x, a1.y, a1.z, a1.w};
      const float wv[8] = {w0.x, w0.y, w0.z, w0.w, w1.x, w1.y, w1.z, w1.w};
#pragma unroll
      for (int j = 0; j < 8; ++j)
#pragma unroll
        for (int i = 0; i < 8; ++i) acc[j][i] = fmaf(av[j], wv[i], acc[j][i]);
    }
  }

  // epilogue: per owned row j: bias -> atomics -> +residual -> 8-lane
  // shuffle LN reduce (lanes l&7 hold the 8 col-groups of this row) -> store
  const float4 be0 = *(const float4*)(be + tc);
  const float4 be1 = *(const float4*)(be + tc + 4);
  const float4 se0 = *(const float4*)(ln_s + tc);
  const float4 se1 = *(const float4*)(ln_s + tc + 4);
  const float4 bi0 = *(const float4*)(ln_b + tc);
  const float4 bi1 = *(const float4*)(ln_b + tc + 4);
  const float bb[8] = {be0.x, be0.y, be0.z, be0.w, be1.x, be1.y, be1.z, be1.w};
  const float ss[8] = {se0.x, se0.y, se0.z, se0.w, se1.x, se1.y, se1.z, se1.w};
  const float ll[8] = {bi0.x, bi0.y, bi0.z, bi0.w, bi1.x, bi1.y, bi1.z, bi1.w};

#pragma unroll
  for (int j = 0; j < 8; ++j) {
    const int row = te + j;              // block-local edge
    const int ge = e0 + row;
    const bool valid = ge < NE;
    const int geC = valid ? ge : NE - 1;
    // residual issued before atomics: vmcnt drains without atomic queue
    const float4 r0 = *(const float4*)(edges + (size_t)geC * H + tc);
    const float4 r1 = *(const float4*)(edges + (size_t)geC * H + tc + 4);
    const float rr[8] = {r0.x, r0.y, r0.z, r0.w, r1.x, r1.y, r1.z, r1.w};
    float* ra = recv_agg + (size_t)rBlk[row] * H + tc;
    float t8[8];
#pragma unroll
    for (int i = 0; i < 8; ++i) {
      const float n = acc[j][i] + bb[i];
      if (valid) atomicAdd(ra + i, n);
      t8[i] = n + rr[i];
    }
    float s1 = 0.f, s2 = 0.f;
#pragma unroll
    for (int i = 0; i < 8; ++i) {
      s1 += t8[i];
      s2 = fmaf(t8[i], t8[i], s2);
    }
    // reduce across the 8 lanes holding this row's col-groups
    s1 += __shfl_xor(s1, 1, 64); s2 += __shfl_xor(s2, 1, 64);
    s1 += __shfl_xor(s1, 2, 64); s2 += __shfl_xor(s2, 2, 64);
    s1 += __shfl_xor(s1, 4, 64); s2 += __shfl_xor(s2, 4, 64);
    const float mean = s1 * (1.0f / 64.0f);
    const float var = s2 * (1.0f / 64.0f) - mean * mean;
    const float rstd = rsqrtf(var + EPS);
    if (valid) {
      float4 o0, o1;
      o0.x = (t8[0] - mean) * rstd * ss[0] + ll[0];
      o0.y = (t8[1] - mean) * rstd * ss[1] + ll[1];
      o0.z = (t8[2] - mean) * rstd * ss[2] + ll[2];
      o0.w = (t8[3] - mean) * rstd * ss[3] + ll[3];
      o1.x = (t8[4] - mean) * rstd * ss[4] + ll[4];
      o1.y = (t8[5] - mean) * rstd * ss[5] + ll[5];
      o1.z = (t8[6] - mean) * rstd * ss[6] + ll[6];
      o1.w = (t8[7] - mean) * rstd * ss[7] + ll[7];
      float* po = edges_out + (size_t)ge * H + tc;
      *(float4*)(po + 0) = o0;
      *(float4*)(po + 4) = o1;
    }
  }
}

// ---- node kernel: unchanged (not the bottleneck, ~30 µs).
__global__ __launch_bounds__(256, 3) void node_tiled(
    const float* __restrict__ nodes, const float* recv_agg,
    const float* __restrict__ Wn, const float* __restrict__ bn,
    const float* __restrict__ ln_s, const float* __restrict__ ln_b,
    float* nodes_out) {
  __shared__ __align__(16) float aT[64 * 64];    // 16 KB: [k-k0][n]
  __shared__ __align__(16) float Wb[128 * 64];   // 32 KB
  const int tid = threadIdx.x;
  const int n0 = blockIdx.x * 64;

#pragma unroll
  for (int t = 0; t < 8; ++t) {
    int ci = t * 256 + tid;
    *(float4*)(&Wb[ci * 4]) = *(const float4*)(Wn + ci * 4);
  }

  float acc[4][4];
#pragma unroll
  for (int j = 0; j < 4; ++j)
#pragma unroll
    for (int i = 0; i < 4; ++i) acc[j][i] = 0.0f;

  const int te = (tid >> 4) * 4;
  const int tc = (tid & 15) * 4;

#pragma unroll
  for (int p = 0; p < 2; ++p) {
    const int k0 = 64 * p;
#pragma unroll
    for (int t = 0; t < 4; ++t) {
      int ci = t * 256 + tid;                     // 1024 float4
      int n = ci & 63, kq = ci >> 6;              // kq 0..15
      int kg = k0 + kq * 4;
      int gn = n0 + n;
      int gnc = gn < NN ? gn : NN - 1;
      const float* src = (kg < 64) ? (nodes + (size_t)gnc * H + kg)
                                   : (recv_agg + (size_t)gnc * H + (kg - 64));
      float4 v = *(const float4*)src;
      aT[(kq * 4 + 0) * 64 + n] = v.x;
      aT[(kq * 4 + 1) * 64 + n] = v.y;
      aT[(kq * 4 + 2) * 64 + n] = v.z;
      aT[(kq * 4 + 3) * 64 + n] = v.w;
    }
    __syncthreads();
#pragma unroll 4
    for (int kk = 0; kk < 64; ++kk) {
      float4 a4 = *(const float4*)(&aT[kk * 64 + te]);
      float4 w4 = *(const float4*)(&Wb[(k0 + kk) * 64 + tc]);
      float av[4] = {a4.x, a4.y, a4.z, a4.w};
      float wv[4] = {w4.x, w4.y, w4.z, w4.w};
#pragma unroll
      for (int j = 0; j < 4; ++j)
#pragma unroll
        for (int i = 0; i < 4; ++i) acc[j][i] += av[j] * wv[i];
    }
    __syncthreads();
  }

  const float4 bev = *(const float4*)(bn + tc);
  const float4 sev = *(const float4*)(ln_s + tc);
  const float4 biv = *(const float4*)(ln_b + tc);
#pragma unroll
  for (int j = 0; j < 4; ++j) {
    int gn = n0 + te + j;
    bool valid = gn < NN;
    float4 nv;
    if (valid) nv = *(const float4*)(nodes + (size_t)gn * H + tc);
    else { nv.x = nv.y = nv.z = nv.w = 0.0f; }
    float t0 = acc[j][0] + bev.x + nv.x;
    float t1 = acc[j][1] + bev.y + nv.y;
    float t2 = acc[j][2] + bev.z + nv.z;
    float t3 = acc[j][3] + bev.w + nv.w;
    float s1 = t0 + t1 + t2 + t3;
    float s2 = t0 * t0 + t1 * t1 + t2 * t2 + t3 * t3;
    s1 += __shfl_xor(s1, 1, 64); s2 += __shfl_xor(s2, 1, 64);
    s1 += __shfl_xor(s1, 2, 64); s2 += __shfl_xor(s2, 2, 64);
    s1 += __shfl_xor(s1, 4, 64); s2 += __shfl_xor(s2, 4, 64);
    s1 += __shfl_xor(s1, 8, 64); s2 += __shfl_xor(s2, 8, 64);
    float mean = s1 * (1.0f / 64.0f);
    float var = s2 * (1.0f / 64.0f) - mean * mean;
    float rstd = rsqrtf(var + EPS);
    if (valid) {
      float4 o;
      o.x = (t0 - mean) * rstd * sev.x + biv.x;
      o.y = (t1 - mean) * rstd * sev.y + biv.y;
      o.z = (t2 - mean) * rstd * sev.z + biv.z;
      o.w = (t3 - mean) * rstd * sev.w + biv.w;
      *(float4*)(nodes_out + (size_t)gn * H + tc) = o;
    }
  }
}

extern "C" void kernel_launch(void* const* d_in, const int* in_sizes, int n_in,
                              void* d_out, int out_size, void* d_ws, size_t ws_size,
                              hipStream_t stream) {
  const float* nodes      = (const float*)d_in[0];
  const float* edges      = (const float*)d_in[1];
  const int*   senders    = (const int*)d_in[2];
  const int*   receivers  = (const int*)d_in[3];
  const float* We         = (const float*)d_in[4];
  const float* be         = (const float*)d_in[5];
  const float* Wn         = (const float*)d_in[6];
  const float* bn         = (const float*)d_in[7];
  const float* ln_n_scale = (const float*)d_in[8];
  const float* ln_n_bias  = (const float*)d_in[9];
  const float* ln_e_scale = (const float*)d_in[10];
  const float* ln_e_bias  = (const float*)d_in[11];

  float* out = (float*)d_out;
  float* nodes_out = out;                       // [NN,64]; doubles as recv_agg
  float* edges_out = out + (size_t)NN * H;      // [NE,64]

  (void)hipMemsetAsync(nodes_out, 0, (size_t)NN * H * sizeof(float), stream);
  edge_rb8<<<(NE + 255) / 256, 256, 0, stream>>>(
      nodes, edges, senders, receivers, We, be, ln_e_scale, ln_e_bias,
      nodes_out, edges_out);
  node_tiled<<<(NN + 63) / 64, 256, 0, stream>>>(nodes, nodes_out, Wn, bn,
                                                 ln_n_scale, ln_n_bias, nodes_out);
}

// Round 6
// 453.127 us; speedup vs baseline: 8.4565x; 4.1886x over previous
//
#include <hip/hip_runtime.h>

#define H 64
#define NN 100000
#define NE 1000000
#define EPS 1e-6f

// ROUND 12: attack the measured wall -- atomic SECTOR amplification.
// Model (validated r6 vs r11): edge-kernel time ~ atomic 32B-sector-touches
// at ~1.1 TB/s; same 1M atomic instrs in both, r6 touched 32 sectors/instr
// (1.02GB excess WRITE_SIZE, 924us), r11 64/instr (2.05GB, 1865us) --
// ratios match to 3%. Fix: per-wave LDS transpose of the pre-residual n
// values, then ONE atomic instruction per edge with lane l adding col l:
// 64 contiguous floats = 8 sectors fully covered = 1x amplification
// (8M touches, 0.26GB). No barriers in the transpose: each wave owns a
// private 4KB slice of aT. LN + edges_out stores stay in the r11 layout
// (6 shuffles/row; stores already full-line). W staged in two 24KB halves
// -> LDS 41KB -> 3 blocks/CU (occupancy 21->37%). acc overwritten in
// place with n (no VGPR growth; VGPR ~100 < 170 cap at min-waves 3).

__global__ __launch_bounds__(256, 3) void edge_rowatomic(
    const float* __restrict__ nodes, const float* __restrict__ edges,
    const int* __restrict__ senders, const int* __restrict__ receivers,
    const float* __restrict__ We, const float* __restrict__ be,
    const float* __restrict__ ln_s, const float* __restrict__ ln_b,
    float* recv_agg, float* __restrict__ edges_out) {
  __shared__ __align__(16) float Wb[96 * 64];   // 24 KB: current W half
  __shared__ __align__(16) float aT[16 * 256];  // 16 KB: [k][edge] per phase;
                                                // reused as 4x4KB wave slices
  __shared__ int rBlk[256];
  const int tid = threadIdx.x;
  const int e0 = blockIdx.x * 256;
  const int myE = e0 + tid;
  const int eC = myE < NE ? myE : NE - 1;  // clamped: loads only
  const int sIdx = senders[eC];
  const int rIdx = receivers[eC];
  rBlk[tid] = rIdx;

  float acc[8][8];
#pragma unroll
  for (int j = 0; j < 8; ++j)
#pragma unroll
    for (int i = 0; i < 8; ++i) acc[j][i] = 0.0f;

  const int te = (tid >> 3) * 8;  // 32 groups x 8 edges
  const int tc = (tid & 7) * 8;   // 8 groups x 8 cols

  // 12 phases of K=16 in two W-halves; phase p region: p<4 edges,
  // p<8 sender, else receiver (regions 64-wide -> region uniform/phase).
#pragma unroll 1
  for (int half = 0; half < 2; ++half) {
    __syncthreads();  // previous half's Wb readers done (no-op at half 0)
#pragma unroll
    for (int t = 0; t < 6; ++t) {
      const int ci = t * 256 + tid;  // 1536 float4 = 96x64 floats
      *(float4*)(&Wb[ci * 4]) =
          *(const float4*)(We + (size_t)half * (96 * 64) + (size_t)ci * 4);
    }
#pragma unroll 1
    for (int p6 = 0; p6 < 6; ++p6) {
      const int p = half * 6 + p6;
      const float* src;
      if (p < 4)      src = edges + (size_t)eC * H + p * 16;
      else if (p < 8) src = nodes + (size_t)sIdx * H + (p - 4) * 16;
      else            src = nodes + (size_t)rIdx * H + (p - 8) * 16;
      // 64B contiguous of this thread's own edge row
      float4 v0 = *(const float4*)(src + 0);
      float4 v1 = *(const float4*)(src + 4);
      float4 v2 = *(const float4*)(src + 8);
      float4 v3 = *(const float4*)(src + 12);
      __syncthreads();  // prev compute done reading aT; W stage visible
      // transpose write: aT[k][e=tid]; bank = tid%32: conflict-free
      aT[0 * 256 + tid] = v0.x;  aT[1 * 256 + tid] = v0.y;
      aT[2 * 256 + tid] = v0.z;  aT[3 * 256 + tid] = v0.w;
      aT[4 * 256 + tid] = v1.x;  aT[5 * 256 + tid] = v1.y;
      aT[6 * 256 + tid] = v1.z;  aT[7 * 256 + tid] = v1.w;
      aT[8 * 256 + tid] = v2.x;  aT[9 * 256 + tid] = v2.y;
      aT[10 * 256 + tid] = v2.z; aT[11 * 256 + tid] = v2.w;
      aT[12 * 256 + tid] = v3.x; aT[13 * 256 + tid] = v3.y;
      aT[14 * 256 + tid] = v3.z; aT[15 * 256 + tid] = v3.w;
      __syncthreads();
      const float* __restrict__ wp = Wb + p6 * (16 * 64);
#pragma unroll 4
      for (int kk = 0; kk < 16; ++kk) {
        float4 a0 = *(const float4*)(&aT[kk * 256 + te + 0]);
        float4 a1 = *(const float4*)(&aT[kk * 256 + te + 4]);
        float4 w0 = *(const float4*)(&wp[kk * 64 + tc + 0]);
        float4 w1 = *(const float4*)(&wp[kk * 64 + tc + 4]);
        const float av[8] = {a0.x, a0.y, a0.z, a0.w, a1.x, a1.y, a1.z, a1.w};
        const float wv[8] = {w0.x, w0.y, w0.z, w0.w, w1.x, w1.y, w1.z, w1.w};
#pragma unroll
        for (int j = 0; j < 8; ++j)
#pragma unroll
          for (int i = 0; i < 8; ++i)
            acc[j][i] = fmaf(av[j], wv[i], acc[j][i]);
      }
    }
  }
  __syncthreads();  // all waves done reading aT: safe to reuse as slices

  // ---- epilogue part 1 (r11 layout): bias -> LN -> store; acc := n ----
  const float4 be0 = *(const float4*)(be + tc);
  const float4 be1 = *(const float4*)(be + tc + 4);
  const float4 se0 = *(const float4*)(ln_s + tc);
  const float4 se1 = *(const float4*)(ln_s + tc + 4);
  const float4 bi0 = *(const float4*)(ln_b + tc);
  const float4 bi1 = *(const float4*)(ln_b + tc + 4);
  const float bb[8] = {be0.x, be0.y, be0.z, be0.w, be1.x, be1.y, be1.z, be1.w};
  const float ss[8] = {se0.x, se0.y, se0.z, se0.w, se1.x, se1.y, se1.z, se1.w};
  const float ll[8] = {bi0.x, bi0.y, bi0.z, bi0.w, bi1.x, bi1.y, bi1.z, bi1.w};

#pragma unroll
  for (int j = 0; j < 8; ++j) {
    const int row = te + j;
    const int ge = e0 + row;
    const bool valid = ge < NE;
    const int geC = valid ? ge : NE - 1;
    const float4 r0 = *(const float4*)(edges + (size_t)geC * H + tc);
    const float4 r1 = *(const float4*)(edges + (size_t)geC * H + tc + 4);
    const float rr[8] = {r0.x, r0.y, r0.z, r0.w, r1.x, r1.y, r1.z, r1.w};
    float t8[8];
#pragma unroll
    for (int i = 0; i < 8; ++i) {
      const float n = acc[j][i] + bb[i];
      acc[j][i] = n;  // keep pre-residual value for the atomic pass
      t8[i] = n + rr[i];
    }
    float s1 = 0.f, s2 = 0.f;
#pragma unroll
    for (int i = 0; i < 8; ++i) { s1 += t8[i]; s2 = fmaf(t8[i], t8[i], s2); }
    // row held by the 8 lanes sharing te: xor 1,2,4
    s1 += __shfl_xor(s1, 1, 64); s2 += __shfl_xor(s2, 1, 64);
    s1 += __shfl_xor(s1, 2, 64); s2 += __shfl_xor(s2, 2, 64);
    s1 += __shfl_xor(s1, 4, 64); s2 += __shfl_xor(s2, 4, 64);
    const float mean = s1 * (1.0f / 64.0f);
    const float var = s2 * (1.0f / 64.0f) - mean * mean;
    const float rstd = rsqrtf(var + EPS);
    if (valid) {
      float4 o0, o1;
      o0.x = (t8[0] - mean) * rstd * ss[0] + ll[0];
      o0.y = (t8[1] - mean) * rstd * ss[1] + ll[1];
      o0.z = (t8[2] - mean) * rstd * ss[2] + ll[2];
      o0.w = (t8[3] - mean) * rstd * ss[3] + ll[3];
      o1.x = (t8[4] - mean) * rstd * ss[4] + ll[4];
      o1.y = (t8[5] - mean) * rstd * ss[5] + ll[5];
      o1.z = (t8[6] - mean) * rstd * ss[6] + ll[6];
      o1.w = (t8[7] - mean) * rstd * ss[7] + ll[7];
      float* po = edges_out + (size_t)ge * H + tc;
      *(float4*)(po + 0) = o0;
      *(float4*)(po + 4) = o1;
    }
  }

  // ---- epilogue part 2: per-wave transpose -> row-contiguous atomics ----
  // Wave wv owns block rows [64wv, 64wv+64) and a private 4KB slice of aT:
  // no cross-wave hazard, no barriers. Per 16-row sub-chunk: the 16 lanes
  // holding those rows (l in [16s,16s+16)) write n to the slice; then all
  // 64 lanes issue one atomic per edge covering the full 256B recv row
  // (8 sectors, 1x amplification). Same-wave LDS ordering + compiler
  // waitcnts make the write->read dependence safe without barriers.
  const int wv = tid >> 6;
  const int l = tid & 63;
  float* slice = aT + wv * 1024;  // 16 rows x 64 cols
#pragma unroll 1
  for (int s = 0; s < 4; ++s) {
    if ((l >> 4) == s) {
      const int rb = ((l >> 3) & 1) * 8;  // slice-row base for this lane
#pragma unroll
      for (int j = 0; j < 8; ++j) {
        float4 x0, x1;
        x0.x = acc[j][0]; x0.y = acc[j][1]; x0.z = acc[j][2]; x0.w = acc[j][3];
        x1.x = acc[j][4]; x1.y = acc[j][5]; x1.z = acc[j][6]; x1.w = acc[j][7];
        *(float4*)(&slice[(rb + j) * 64 + tc + 0]) = x0;
        *(float4*)(&slice[(rb + j) * 64 + tc + 4]) = x1;
      }
    }
#pragma unroll 4
    for (int e = 0; e < 16; ++e) {
      const int row = wv * 64 + s * 16 + e;
      const int ge = e0 + row;
      if (ge < NE) {  // uniform per instruction
        const float v = slice[e * 64 + l];  // stride-1: 2-way, free
        atomicAdd(recv_agg + (size_t)rBlk[row] * H + l, v);
      }
    }
  }
}

// ---- node kernel: unchanged (not the bottleneck, ~30 µs).
__global__ __launch_bounds__(256, 3) void node_tiled(
    const float* __restrict__ nodes, const float* recv_agg,
    const float* __restrict__ Wn, const float* __restrict__ bn,
    const float* __restrict__ ln_s, const float* __restrict__ ln_b,
    float* nodes_out) {
  __shared__ __align__(16) float aT[64 * 64];    // 16 KB: [k-k0][n]
  __shared__ __align__(16) float Wb[128 * 64];   // 32 KB
  const int tid = threadIdx.x;
  const int n0 = blockIdx.x * 64;

#pragma unroll
  for (int t = 0; t < 8; ++t) {
    int ci = t * 256 + tid;
    *(float4*)(&Wb[ci * 4]) = *(const float4*)(Wn + ci * 4);
  }

  float acc[4][4];
#pragma unroll
  for (int j = 0; j < 4; ++j)
#pragma unroll
    for (int i = 0; i < 4; ++i) acc[j][i] = 0.0f;

  const int te = (tid >> 4) * 4;
  const int tc = (tid & 15) * 4;

#pragma unroll
  for (int p = 0; p < 2; ++p) {
    const int k0 = 64 * p;
#pragma unroll
    for (int t = 0; t < 4; ++t) {
      int ci = t * 256 + tid;                     // 1024 float4
      int n = ci & 63, kq = ci >> 6;              // kq 0..15
      int kg = k0 + kq * 4;
      int gn = n0 + n;
      int gnc = gn < NN ? gn : NN - 1;
      const float* src = (kg < 64) ? (nodes + (size_t)gnc * H + kg)
                                   : (recv_agg + (size_t)gnc * H + (kg - 64));
      float4 v = *(const float4*)src;
      aT[(kq * 4 + 0) * 64 + n] = v.x;
      aT[(kq * 4 + 1) * 64 + n] = v.y;
      aT[(kq * 4 + 2) * 64 + n] = v.z;
      aT[(kq * 4 + 3) * 64 + n] = v.w;
    }
    __syncthreads();
#pragma unroll 4
    for (int kk = 0; kk < 64; ++kk) {
      float4 a4 = *(const float4*)(&aT[kk * 64 + te]);
      float4 w4 = *(const float4*)(&Wb[(k0 + kk) * 64 + tc]);
      float av[4] = {a4.x, a4.y, a4.z, a4.w};
      float wv[4] = {w4.x, w4.y, w4.z, w4.w};
#pragma unroll
      for (int j = 0; j < 4; ++j)
#pragma unroll
        for (int i = 0; i < 4; ++i) acc[j][i] += av[j] * wv[i];
    }
    __syncthreads();
  }

  const float4 bev = *(const float4*)(bn + tc);
  const float4 sev = *(const float4*)(ln_s + tc);
  const float4 biv = *(const float4*)(ln_b + tc);
#pragma unroll
  for (int j = 0; j < 4; ++j) {
    int gn = n0 + te + j;
    bool valid = gn < NN;
    float4 nv;
    if (valid) nv = *(const float4*)(nodes + (size_t)gn * H + tc);
    else { nv.x = nv.y = nv.z = nv.w = 0.0f; }
    float t0 = acc[j][0] + bev.x + nv.x;
    float t1 = acc[j][1] + bev.y + nv.y;
    float t2 = acc[j][2] + bev.z + nv.z;
    float t3 = acc[j][3] + bev.w + nv.w;
    float s1 = t0 + t1 + t2 + t3;
    float s2 = t0 * t0 + t1 * t1 + t2 * t2 + t3 * t3;
    s1 += __shfl_xor(s1, 1, 64); s2 += __shfl_xor(s2, 1, 64);
    s1 += __shfl_xor(s1, 2, 64); s2 += __shfl_xor(s2, 2, 64);
    s1 += __shfl_xor(s1, 4, 64); s2 += __shfl_xor(s2, 4, 64);
    s1 += __shfl_xor(s1, 8, 64); s2 += __shfl_xor(s2, 8, 64);
    float mean = s1 * (1.0f / 64.0f);
    float var = s2 * (1.0f / 64.0f) - mean * mean;
    float rstd = rsqrtf(var + EPS);
    if (valid) {
      float4 o;
      o.x = (t0 - mean) * rstd * sev.x + biv.x;
      o.y = (t1 - mean) * rstd * sev.y + biv.y;
      o.z = (t2 - mean) * rstd * sev.z + biv.z;
      o.w = (t3 - mean) * rstd * sev.w + biv.w;
      *(float4*)(nodes_out + (size_t)gn * H + tc) = o;
    }
  }
}

extern "C" void kernel_launch(void* const* d_in, const int* in_sizes, int n_in,
                              void* d_out, int out_size, void* d_ws, size_t ws_size,
                              hipStream_t stream) {
  const float* nodes      = (const float*)d_in[0];
  const float* edges      = (const float*)d_in[1];
  const int*   senders    = (const int*)d_in[2];
  const int*   receivers  = (const int*)d_in[3];
  const float* We         = (const float*)d_in[4];
  const float* be         = (const float*)d_in[5];
  const float* Wn         = (const float*)d_in[6];
  const float* bn         = (const float*)d_in[7];
  const float* ln_n_scale = (const float*)d_in[8];
  const float* ln_n_bias  = (const float*)d_in[9];
  const float* ln_e_scale = (const float*)d_in[10];
  const float* ln_e_bias  = (const float*)d_in[11];

  float* out = (float*)d_out;
  float* nodes_out = out;                       // [NN,64]; doubles as recv_agg
  float* edges_out = out + (size_t)NN * H;      // [NE,64]

  (void)hipMemsetAsync(nodes_out, 0, (size_t)NN * H * sizeof(float), stream);
  edge_rowatomic<<<(NE + 255) / 256, 256, 0, stream>>>(
      nodes, edges, senders, receivers, We, be, ln_e_scale, ln_e_bias,
      nodes_out, edges_out);
  node_tiled<<<(NN + 63) / 64, 256, 0, stream>>>(nodes, nodes_out, Wn, bn,
                                                 ln_n_scale, ln_n_bias, nodes_out);
}